// Round 10
// baseline (212.817 us; speedup 1.0000x reference)
//
#include <hip/hip_runtime.h>
#include <hip/hip_bf16.h>
#include <math.h>

// ---------------- constants ----------------
#define HDIM 128
#define SCAN_B 256
#define NBLK 256          // edge blocks for hist/scatter passes

typedef short bfrag __attribute__((ext_vector_type(8)));   // 8 bf16 (4 VGPRs)
typedef float f32x4 __attribute__((ext_vector_type(4)));   // 4 fp32 acc

__device__ inline unsigned short f2bf_rne(float x) {
    unsigned u = __float_as_uint(x);
    u = (u + 0x7fffu + ((u >> 16) & 1u)) >> 16;
    return (unsigned short)u;
}
__device__ inline float bf_lo(unsigned u) { return __uint_as_float(u << 16); }
__device__ inline float bf_hi(unsigned u) { return __uint_as_float(u & 0xffff0000u); }

// ---------------- device bodies ----------------

// Pass A: per-block LDS histogram over coarse buckets (dst>>8); no global atomics.
__device__ inline void hist_body(int b, const int* __restrict__ dst,
                                 int* __restrict__ hist, int E, int chunk, int nbuck) {
    __shared__ int hl[256];
    int t = threadIdx.x;
    hl[t] = 0;
    __syncthreads();
    int start = b * chunk, end = min(E, start + chunk);
    for (int e = start + t; e < end; e += 256) atomicAdd(&hl[dst[e] >> 8], 1);
    __syncthreads();
    if (t < nbuck) hist[t * NBLK + b] = hl[t];
}

// W -> fragment-ordered bf16 hi/lo, column-permuted: physical slot (nt, lm)
// carries logical column n_l = lm*8 + nt (so epilogue stores are 16B packed).
__device__ inline void wfrag_body(int b, const float* __restrict__ W1,
                                  const float* __restrict__ W2,
                                  unsigned short* __restrict__ w1h,
                                  unsigned short* __restrict__ w1l,
                                  unsigned short* __restrict__ w2h,
                                  unsigned short* __restrict__ w2l) {
    const float* W = (b < 64) ? W1 : W2;
    unsigned short* whi = (b < 64) ? w1h : w2h;
    unsigned short* wlo = (b < 64) ? w1l : w2l;
    int idx = (b & 63) * 256 + threadIdx.x;     // 0..16383
    int k = idx >> 7;
    int n = idx & 127;
    int kt = k >> 5, q = (k >> 3) & 3, j = k & 7;
    int lm = n >> 3, nt = n & 7;
    int lane = q * 16 + lm;
    int o = ((kt * 8 + nt) * 64 + lane) * 8 + j;
    float x = W[idx];
    unsigned short hb = f2bf_rne(x);
    float hf = __uint_as_float(((unsigned)hb) << 16);
    unsigned short lb = f2bf_rne(x - hf);
    whi[o] = hb;
    wlo[o] = lb;
}

// Pass C: scatter edges into bucket-sorted order via LDS cursors.
// Packed entry: src (16b, N=50000<65536) | (dst&255)<<16  -- 4B/edge.
__device__ inline void scatter_body(int b, const int* __restrict__ srcv,
                                    const int* __restrict__ dstv,
                                    const int* __restrict__ hscan,
                                    int* __restrict__ sorted,
                                    int E, int chunk, int nbuck) {
    __shared__ int cur[256];
    int t = threadIdx.x;
    if (t < nbuck) cur[t] = hscan[t * NBLK + b];
    __syncthreads();
    int start = b * chunk, end = min(E, start + chunk);
    for (int e = start + t; e < end; e += 256) {
        int d = dstv[e];
        int pos = atomicAdd(&cur[d >> 8], 1);
        sorted[pos] = srcv[e] | ((d & 255) << 16);
    }
}

// MFMA GEMM (fp32 A), 64-row tiles, split 3-MFMA: C ~= Ah*Wh + Al*Wh + Ah*Wl
#define GBM 64
__device__ inline void gemm_f32_body(int b, const float* __restrict__ A,
                                     const unsigned short* __restrict__ whi,
                                     const unsigned short* __restrict__ wlo,
                                     unsigned short* __restrict__ C, int Nrows) {
    int tid = threadIdx.x;
    int w = tid >> 6, L = tid & 63;
    int lm = L & 15, lq = L >> 4;
    int row0 = b * GBM + w * 16;

    f32x4 acc[8];
#pragma unroll
    for (int nt = 0; nt < 8; ++nt) acc[nt] = (f32x4)(0.f);

#pragma unroll
    for (int kt = 0; kt < 4; ++kt) {
        int gr = row0 + lm;
        float4 v0 = make_float4(0.f, 0.f, 0.f, 0.f);
        float4 v1 = v0;
        if (gr < Nrows) {
            const float* p = &A[(size_t)gr * HDIM + kt * 32 + lq * 8];
            v0 = *(const float4*)p;
            v1 = *(const float4*)(p + 4);
        }
        float xv[8] = {v0.x, v0.y, v0.z, v0.w, v1.x, v1.y, v1.z, v1.w};
        bfrag ah, al;
#pragma unroll
        for (int j = 0; j < 8; ++j) {
            float x = xv[j];
            unsigned short hb = f2bf_rne(x);
            float hf = __uint_as_float(((unsigned)hb) << 16);
            unsigned short lb = f2bf_rne(x - hf);
            ah[j] = (short)hb;
            al[j] = (short)lb;
        }
#pragma unroll
        for (int nt = 0; nt < 8; ++nt) {
            int o = ((kt * 8 + nt) * 64 + L) * 8;
            bfrag wh = *(const bfrag*)&whi[o];
            bfrag wl = *(const bfrag*)&wlo[o];
            acc[nt] = __builtin_amdgcn_mfma_f32_16x16x32_bf16(ah, wh, acc[nt], 0, 0, 0);
            acc[nt] = __builtin_amdgcn_mfma_f32_16x16x32_bf16(al, wh, acc[nt], 0, 0, 0);
            acc[nt] = __builtin_amdgcn_mfma_f32_16x16x32_bf16(ah, wl, acc[nt], 0, 0, 0);
        }
    }

#pragma unroll
    for (int i = 0; i < 4; ++i) {
        int gr = row0 + lq * 4 + i;
        if (gr < Nrows) {
            bfrag e;
#pragma unroll
            for (int nt = 0; nt < 8; ++nt) e[nt] = (short)f2bf_rne(acc[nt][i]);
            *(bfrag*)&C[(size_t)gr * HDIM + lm * 8] = e;
        }
    }
}

// ---------------- megakernel 1: hist || wfrag ----------------
__global__ __launch_bounds__(256) void mega1_kernel(const int* __restrict__ dst,
                                                    int* __restrict__ hist, int E,
                                                    int chunk, int nbuck,
                                                    const float* __restrict__ W1,
                                                    const float* __restrict__ W2,
                                                    unsigned short* __restrict__ w1h,
                                                    unsigned short* __restrict__ w1l,
                                                    unsigned short* __restrict__ w2h,
                                                    unsigned short* __restrict__ w2l) {
    int b = blockIdx.x;
    if (b < NBLK) hist_body(b, dst, hist, E, chunk, nbuck);
    else wfrag_body(b - NBLK, W1, W2, w1h, w1l, w2h, w2l);
}

// ---------------- megakernel 3: scatter || gemm_f32(layer1) ----------------
__global__ __launch_bounds__(256) void mega3_kernel(const int* __restrict__ srcv,
                                                    const int* __restrict__ dstv,
                                                    const int* __restrict__ hscan,
                                                    int* __restrict__ sorted,
                                                    int E, int chunk, int nbuck,
                                                    const float* __restrict__ A,
                                                    const unsigned short* __restrict__ whi,
                                                    const unsigned short* __restrict__ wlo,
                                                    unsigned short* __restrict__ C, int Nrows) {
    int b = blockIdx.x;
    if (b < NBLK) scatter_body(b, srcv, dstv, hscan, sorted, E, chunk, nbuck);
    else gemm_f32_body(b - NBLK, A, whi, wlo, C, Nrows);
}

// ---------------- scan: phase 1 (block-local inclusive + block sums) ----------------
__global__ __launch_bounds__(SCAN_B) void scan1_kernel(const int* __restrict__ in,
                                                       int* __restrict__ out,
                                                       int* __restrict__ sums, int n) {
    __shared__ int s[SCAN_B];
    int t = threadIdx.x;
    int idx = blockIdx.x * SCAN_B + t;
    int v = (idx < n) ? in[idx] : 0;
    s[t] = v;
    __syncthreads();
    for (int off = 1; off < SCAN_B; off <<= 1) {
        int x = (t >= off) ? s[t - off] : 0;
        __syncthreads();
        s[t] += x;
        __syncthreads();
    }
    if (idx < n) out[idx] = s[t];
    if (t == SCAN_B - 1) sums[blockIdx.x] = s[t];
}

// scan phase 2+3 fused: every block re-scans the (raw) block sums in LDS,
// takes its own exclusive base, finalizes out[] to global exclusive scan.
__global__ __launch_bounds__(SCAN_B) void scan3_kernel(const int* __restrict__ in,
                                                       int* __restrict__ out,
                                                       const int* __restrict__ sums,
                                                       int n, int nb) {
    __shared__ int s[SCAN_B];
    int t = threadIdx.x;
    int v = (t < nb) ? sums[t] : 0;
    s[t] = v;
    __syncthreads();
    for (int off = 1; off < SCAN_B; off <<= 1) {
        int x = (t >= off) ? s[t - off] : 0;
        __syncthreads();
        s[t] += x;
        __syncthreads();
    }
    int base = (blockIdx.x > 0) ? s[blockIdx.x - 1] : 0;
    int idx = blockIdx.x * SCAN_B + t;
    if (idx < n) out[idx] = out[idx] - in[idx] + base;
}

// ---------------- Pass D: per-bucket CSR build (LDS atomics only) ----------------
__global__ __launch_bounds__(256) void csr_kernel(const int* __restrict__ sorted,
                                                  const int* __restrict__ hscan,
                                                  int* __restrict__ rowstart,
                                                  float* __restrict__ dinv,
                                                  int* __restrict__ csr,
                                                  int N, int E, int nbuck) {
    __shared__ int cnt[256];
    __shared__ int s[256];
    __shared__ int cur[256];
    int b = blockIdx.x;
    int t = threadIdx.x;
    int start = hscan[b * NBLK];
    int end = (b + 1 < nbuck) ? hscan[(b + 1) * NBLK] : E;
    cnt[t] = 0;
    __syncthreads();
    for (int e = start + t; e < end; e += 256)
        atomicAdd(&cnt[(sorted[e] >> 16) & 255], 1);
    __syncthreads();
    int v = cnt[t];
    s[t] = v;
    __syncthreads();
    for (int off = 1; off < 256; off <<= 1) {
        int x = (t >= off) ? s[t - off] : 0;
        __syncthreads();
        s[t] += x;
        __syncthreads();
    }
    int excl = s[t] - v;
    int node = b * 256 + t;
    if (node < N) {
        rowstart[node] = start + excl;
        dinv[node] = rsqrtf((float)(v + 1));   // +1 self-loop
    }
    if (b == nbuck - 1 && t == 0) rowstart[N] = E;
    cur[t] = start + excl;
    __syncthreads();
    for (int e = start + t; e < end; e += 256) {
        int ed = sorted[e];
        int pos = atomicAdd(&cur[(ed >> 16) & 255], 1);
        csr[pos] = ed & 0xFFFF;
    }
}

// ---------------- gather macros (params must not collide with .x/.y/.z/.w) ----------------
#define QACC(ACCP, UV, WT)                                 \
    ACCP[0] = fmaf(WT, bf_lo((UV).x), ACCP[0]);            \
    ACCP[1] = fmaf(WT, bf_hi((UV).x), ACCP[1]);            \
    ACCP[2] = fmaf(WT, bf_lo((UV).y), ACCP[2]);            \
    ACCP[3] = fmaf(WT, bf_hi((UV).y), ACCP[3]);            \
    ACCP[4] = fmaf(WT, bf_lo((UV).z), ACCP[4]);            \
    ACCP[5] = fmaf(WT, bf_hi((UV).z), ACCP[5]);            \
    ACCP[6] = fmaf(WT, bf_lo((UV).w), ACCP[6]);            \
    ACCP[7] = fmaf(WT, bf_hi((UV).w), ACCP[7]);

// single-chain drain, 8/4/2/1 deep
__device__ inline void qgather(const uint4* __restrict__ m4,
                               const int* __restrict__ csr,
                               const float* __restrict__ dinv,
                               int p, int pend, int t, float* acc) {
    for (; p + 8 <= pend; p += 8) {
        int s0 = csr[p], s1 = csr[p + 1], s2 = csr[p + 2], s3 = csr[p + 3];
        int s4 = csr[p + 4], s5 = csr[p + 5], s6 = csr[p + 6], s7 = csr[p + 7];
        float w0 = dinv[s0], w1 = dinv[s1], w2 = dinv[s2], w3 = dinv[s3];
        float w4 = dinv[s4], w5 = dinv[s5], w6 = dinv[s6], w7 = dinv[s7];
        uint4 u0 = m4[(size_t)s0 * 16 + t];
        uint4 u1 = m4[(size_t)s1 * 16 + t];
        uint4 u2 = m4[(size_t)s2 * 16 + t];
        uint4 u3 = m4[(size_t)s3 * 16 + t];
        uint4 u4 = m4[(size_t)s4 * 16 + t];
        uint4 u5 = m4[(size_t)s5 * 16 + t];
        uint4 u6 = m4[(size_t)s6 * 16 + t];
        uint4 u7 = m4[(size_t)s7 * 16 + t];
        QACC(acc, u0, w0); QACC(acc, u1, w1); QACC(acc, u2, w2); QACC(acc, u3, w3);
        QACC(acc, u4, w4); QACC(acc, u5, w5); QACC(acc, u6, w6); QACC(acc, u7, w7);
    }
    if (p + 4 <= pend) {
        int s0 = csr[p], s1 = csr[p + 1], s2 = csr[p + 2], s3 = csr[p + 3];
        float w0 = dinv[s0], w1 = dinv[s1], w2 = dinv[s2], w3 = dinv[s3];
        uint4 u0 = m4[(size_t)s0 * 16 + t];
        uint4 u1 = m4[(size_t)s1 * 16 + t];
        uint4 u2 = m4[(size_t)s2 * 16 + t];
        uint4 u3 = m4[(size_t)s3 * 16 + t];
        QACC(acc, u0, w0); QACC(acc, u1, w1); QACC(acc, u2, w2); QACC(acc, u3, w3);
        p += 4;
    }
    if (p + 2 <= pend) {
        int s0 = csr[p], s1 = csr[p + 1];
        float w0 = dinv[s0], w1 = dinv[s1];
        uint4 u0 = m4[(size_t)s0 * 16 + t];
        uint4 u1 = m4[(size_t)s1 * 16 + t];
        QACC(acc, u0, w0); QACC(acc, u1, w1);
        p += 2;
    }
    if (p < pend) {
        int s0 = csr[p];
        float w0 = dinv[s0];
        uint4 u0 = m4[(size_t)s0 * 16 + t];
        QACC(acc, u0, w0);
    }
}

// two interleaved chains per quarter: 8 gathers in flight, degree-averaged.
// Accumulation order into each acc register is csr order -> bit-identical to serial.
__device__ inline void qgather2(const uint4* __restrict__ m4,
                                const int* __restrict__ csr,
                                const float* __restrict__ dinv,
                                int pA, int eA, int pB, int eB, int t,
                                float* accA, float* accB) {
    while (pA + 4 <= eA && pB + 4 <= eB) {
        int a0 = csr[pA], a1 = csr[pA + 1], a2 = csr[pA + 2], a3 = csr[pA + 3];
        int b0 = csr[pB], b1 = csr[pB + 1], b2 = csr[pB + 2], b3 = csr[pB + 3];
        float va0 = dinv[a0], va1 = dinv[a1], va2 = dinv[a2], va3 = dinv[a3];
        float vb0 = dinv[b0], vb1 = dinv[b1], vb2 = dinv[b2], vb3 = dinv[b3];
        uint4 ua0 = m4[(size_t)a0 * 16 + t];
        uint4 ua1 = m4[(size_t)a1 * 16 + t];
        uint4 ua2 = m4[(size_t)a2 * 16 + t];
        uint4 ua3 = m4[(size_t)a3 * 16 + t];
        uint4 ub0 = m4[(size_t)b0 * 16 + t];
        uint4 ub1 = m4[(size_t)b1 * 16 + t];
        uint4 ub2 = m4[(size_t)b2 * 16 + t];
        uint4 ub3 = m4[(size_t)b3 * 16 + t];
        QACC(accA, ua0, va0); QACC(accA, ua1, va1); QACC(accA, ua2, va2); QACC(accA, ua3, va3);
        QACC(accB, ub0, vb0); QACC(accB, ub1, vb1); QACC(accB, ub2, vb2); QACC(accB, ub3, vb3);
        pA += 4; pB += 4;
    }
    qgather(m4, csr, dinv, pA, eA, t, accA);
    qgather(m4, csr, dinv, pB, eB, t, accB);
}

// ---------------- fused agg(layer1) + gemm(layer2): 32 nodes/block ----------------
__global__ __launch_bounds__(256) void agg_gemm_kernel(
        const uint4* __restrict__ m4,
        const int* __restrict__ rowstart,
        const int* __restrict__ csr,
        const float* __restrict__ dinv,
        const float* __restrict__ bias,
        const unsigned short* __restrict__ whi,   // W2 frags
        const unsigned short* __restrict__ wlo,
        uint4* __restrict__ out_m, int n) {
    __shared__ unsigned short hbuf[32][HDIM + 8];   // bf16 h tile (+16B pad)
    __shared__ float cbuf[32][HDIM + 4];            // fp32 C tile (+16B pad)
    int t = threadIdx.x & 15;
    int nl = threadIdx.x >> 4;                      // 0..15
    int nodeA = blockIdx.x * 32 + nl;
    int nodeB = nodeA + 16;
    bool vA = nodeA < n, vB = nodeB < n;

    // ---- agg phase (two chains per quarter) ----
    float accA[8], accB[8];
    float ddA = 0.f, ddB = 0.f;
    int pA = 0, eA = 0, pB = 0, eB = 0;
    if (vA) {
        ddA = dinv[nodeA];
        uint4 u = m4[(size_t)nodeA * 16 + t];
        accA[0] = ddA * bf_lo(u.x); accA[1] = ddA * bf_hi(u.x);
        accA[2] = ddA * bf_lo(u.y); accA[3] = ddA * bf_hi(u.y);
        accA[4] = ddA * bf_lo(u.z); accA[5] = ddA * bf_hi(u.z);
        accA[6] = ddA * bf_lo(u.w); accA[7] = ddA * bf_hi(u.w);
        pA = rowstart[nodeA]; eA = rowstart[nodeA + 1];
    } else {
#pragma unroll
        for (int j = 0; j < 8; ++j) accA[j] = 0.f;
    }
    if (vB) {
        ddB = dinv[nodeB];
        uint4 u = m4[(size_t)nodeB * 16 + t];
        accB[0] = ddB * bf_lo(u.x); accB[1] = ddB * bf_hi(u.x);
        accB[2] = ddB * bf_lo(u.y); accB[3] = ddB * bf_hi(u.y);
        accB[4] = ddB * bf_lo(u.z); accB[5] = ddB * bf_hi(u.z);
        accB[6] = ddB * bf_lo(u.w); accB[7] = ddB * bf_hi(u.w);
        pB = rowstart[nodeB]; eB = rowstart[nodeB + 1];
    } else {
#pragma unroll
        for (int j = 0; j < 8; ++j) accB[j] = 0.f;
    }
    qgather2(m4, csr, dinv, pA, eA, pB, eB, t, accA, accB);

    float4 b0 = *(const float4*)&bias[t * 8];
    float4 b1 = *(const float4*)&bias[t * 8 + 4];
    float bb[8] = {b0.x, b0.y, b0.z, b0.w, b1.x, b1.y, b1.z, b1.w};
    unsigned short hA[8], hB[8];
#pragma unroll
    for (int j = 0; j < 8; ++j) {
        hA[j] = vA ? f2bf_rne(fmaxf(fmaf(ddA, accA[j], bb[j]), 0.f)) : (unsigned short)0;
        hB[j] = vB ? f2bf_rne(fmaxf(fmaf(ddB, accB[j], bb[j]), 0.f)) : (unsigned short)0;
    }
    *(uint4*)&hbuf[nl][t * 8] = *(uint4*)hA;
    *(uint4*)&hbuf[nl + 16][t * 8] = *(uint4*)hB;
    __syncthreads();

    // ---- gemm phase: 32x128 @ 128x128; wave w does col tiles {2w,2w+1}, both row tiles ----
    int w = threadIdx.x >> 6, L = threadIdx.x & 63;
    int lm = L & 15, lq = L >> 4;
    f32x4 acc2[2][2];
    acc2[0][0] = (f32x4)(0.f); acc2[0][1] = (f32x4)(0.f);
    acc2[1][0] = (f32x4)(0.f); acc2[1][1] = (f32x4)(0.f);
#pragma unroll
    for (int kt = 0; kt < 4; ++kt) {
        bfrag a0r = *(const bfrag*)&hbuf[lm][kt * 32 + lq * 8];
        bfrag a1r = *(const bfrag*)&hbuf[16 + lm][kt * 32 + lq * 8];
#pragma unroll
        for (int q2 = 0; q2 < 2; ++q2) {
            int nt = w * 2 + q2;
            int o = ((kt * 8 + nt) * 64 + L) * 8;
            bfrag wh = *(const bfrag*)&whi[o];
            bfrag wl = *(const bfrag*)&wlo[o];
            acc2[0][q2] = __builtin_amdgcn_mfma_f32_16x16x32_bf16(a0r, wh, acc2[0][q2], 0, 0, 0);
            acc2[0][q2] = __builtin_amdgcn_mfma_f32_16x16x32_bf16(a0r, wl, acc2[0][q2], 0, 0, 0);
            acc2[1][q2] = __builtin_amdgcn_mfma_f32_16x16x32_bf16(a1r, wh, acc2[1][q2], 0, 0, 0);
            acc2[1][q2] = __builtin_amdgcn_mfma_f32_16x16x32_bf16(a1r, wl, acc2[1][q2], 0, 0, 0);
        }
    }
    // C/D: col(in tile)=lm, row=lq*4+i ; logical col = lm*8+nt
#pragma unroll
    for (int mt = 0; mt < 2; ++mt)
#pragma unroll
        for (int q2 = 0; q2 < 2; ++q2) {
            int nt = w * 2 + q2;
#pragma unroll
            for (int i = 0; i < 4; ++i)
                cbuf[mt * 16 + lq * 4 + i][lm * 8 + nt] = acc2[mt][q2][i];
        }
    __syncthreads();

    // ---- repack + round + store (two rows per thread) ----
    if (vA) {
        float4 r0 = *(const float4*)&cbuf[nl][t * 8];
        float4 r1 = *(const float4*)&cbuf[nl][t * 8 + 4];
        unsigned short ev[8];
        ev[0] = f2bf_rne(r0.x); ev[1] = f2bf_rne(r0.y);
        ev[2] = f2bf_rne(r0.z); ev[3] = f2bf_rne(r0.w);
        ev[4] = f2bf_rne(r1.x); ev[5] = f2bf_rne(r1.y);
        ev[6] = f2bf_rne(r1.z); ev[7] = f2bf_rne(r1.w);
        out_m[(size_t)nodeA * 16 + t] = *(uint4*)ev;
    }
    if (vB) {
        float4 r0 = *(const float4*)&cbuf[nl + 16][t * 8];
        float4 r1 = *(const float4*)&cbuf[nl + 16][t * 8 + 4];
        unsigned short ev[8];
        ev[0] = f2bf_rne(r0.x); ev[1] = f2bf_rne(r0.y);
        ev[2] = f2bf_rne(r0.z); ev[3] = f2bf_rne(r0.w);
        ev[4] = f2bf_rne(r1.x); ev[5] = f2bf_rne(r1.y);
        ev[6] = f2bf_rne(r1.z); ev[7] = f2bf_rne(r1.w);
        out_m[(size_t)nodeB * 16 + t] = *(uint4*)ev;
    }
}

// ---------------- agg layer 2 fused with global max pool: 32 nodes/block ----------------
__global__ __launch_bounds__(256) void agg_pool_kernel(const uint4* __restrict__ m4,
                                                       const int* __restrict__ rowstart,
                                                       const int* __restrict__ csr,
                                                       const float* __restrict__ dinv,
                                                       const float* __restrict__ bias,
                                                       const int* __restrict__ batch,
                                                       unsigned int* __restrict__ g, int n) {
    __shared__ float smx[32][HDIM];
    __shared__ int sgid[32];
    int t = threadIdx.x & 15;
    int nl = threadIdx.x >> 4;
    int nodeA = blockIdx.x * 32 + nl;
    int nodeB = nodeA + 16;
    bool vA = nodeA < n, vB = nodeB < n;

    float accA[8], accB[8];
    float ddA = 0.f, ddB = 0.f;
    int pA = 0, eA = 0, pB = 0, eB = 0;
    if (vA) {
        ddA = dinv[nodeA];
        uint4 u = m4[(size_t)nodeA * 16 + t];
        accA[0] = ddA * bf_lo(u.x); accA[1] = ddA * bf_hi(u.x);
        accA[2] = ddA * bf_lo(u.y); accA[3] = ddA * bf_hi(u.y);
        accA[4] = ddA * bf_lo(u.z); accA[5] = ddA * bf_hi(u.z);
        accA[6] = ddA * bf_lo(u.w); accA[7] = ddA * bf_hi(u.w);
        pA = rowstart[nodeA]; eA = rowstart[nodeA + 1];
    } else {
#pragma unroll
        for (int j = 0; j < 8; ++j) accA[j] = 0.f;
    }
    if (vB) {
        ddB = dinv[nodeB];
        uint4 u = m4[(size_t)nodeB * 16 + t];
        accB[0] = ddB * bf_lo(u.x); accB[1] = ddB * bf_hi(u.x);
        accB[2] = ddB * bf_lo(u.y); accB[3] = ddB * bf_hi(u.y);
        accB[4] = ddB * bf_lo(u.z); accB[5] = ddB * bf_hi(u.z);
        accB[6] = ddB * bf_lo(u.w); accB[7] = ddB * bf_hi(u.w);
        pB = rowstart[nodeB]; eB = rowstart[nodeB + 1];
    } else {
#pragma unroll
        for (int j = 0; j < 8; ++j) accB[j] = 0.f;
    }
    qgather2(m4, csr, dinv, pA, eA, pB, eB, t, accA, accB);

    float4 b0 = *(const float4*)&bias[t * 8];
    float4 b1 = *(const float4*)&bias[t * 8 + 4];
    float bb[8] = {b0.x, b0.y, b0.z, b0.w, b1.x, b1.y, b1.z, b1.w};
#pragma unroll
    for (int j = 0; j < 8; ++j) {
        smx[nl][t * 8 + j] = vA ? fmaxf(fmaf(ddA, accA[j], bb[j]), 0.f) : 0.f;
        smx[nl + 16][t * 8 + j] = vB ? fmaxf(fmaf(ddB, accB[j], bb[j]), 0.f) : 0.f;
    }
    if (t == 0) {
        sgid[nl] = vA ? batch[nodeA] : -1;
        sgid[nl + 16] = vB ? batch[nodeB] : -1;
    }
    __syncthreads();
    if (threadIdx.x < HDIM) {
        int c = threadIdx.x;
        int curg = -1;
        float run = 0.f;
#pragma unroll
        for (int r = 0; r < 32; ++r) {
            int gg = sgid[r];
            if (gg < 0) continue;
            if (gg != curg) {
                if (curg >= 0) atomicMax(&g[curg * HDIM + c], __float_as_uint(run));
                curg = gg;
                run = smx[r][c];
            } else {
                run = fmaxf(run, smx[r][c]);
            }
        }
        if (curg >= 0) atomicMax(&g[curg * HDIM + c], __float_as_uint(run));
    }
}

// ---------------- MLP head + log_softmax ----------------
__global__ __launch_bounds__(128) void mlp_kernel(const unsigned int* __restrict__ gbits,
                                                  const float* __restrict__ W3,
                                                  const float* __restrict__ b3,
                                                  const float* __restrict__ W4,
                                                  const float* __restrict__ b4,
                                                  float* __restrict__ out) {
    __shared__ float gs[HDIM];
    __shared__ float r0[HDIM];
    __shared__ float r1[HDIM];
    int j = threadIdx.x;
    int b = blockIdx.x;
    gs[j] = __uint_as_float(gbits[b * HDIM + j]);
    __syncthreads();
    float acc = b3[j];
#pragma unroll 8
    for (int k = 0; k < HDIM; ++k) acc = fmaf(gs[k], W3[k * HDIM + j], acc);
    float z = fmaxf(acc, 0.f);
    r0[j] = z * W4[j * 2 + 0];
    r1[j] = z * W4[j * 2 + 1];
    __syncthreads();
    for (int off = 64; off > 0; off >>= 1) {
        if (j < off) {
            r0[j] += r0[j + off];
            r1[j] += r1[j + off];
        }
        __syncthreads();
    }
    if (j == 0) {
        float l0 = r0[0] + b4[0];
        float l1 = r1[0] + b4[1];
        float mx = fmaxf(l0, l1);
        float lse = mx + logf(expf(l0 - mx) + expf(l1 - mx));
        out[b * 2 + 0] = l0 - lse;
        out[b * 2 + 1] = l1 - lse;
    }
}

extern "C" void kernel_launch(void* const* d_in, const int* in_sizes, int n_in,
                              void* d_out, int out_size, void* d_ws, size_t ws_size,
                              hipStream_t stream) {
    const float* x  = (const float*)d_in[0];
    const float* W1 = (const float*)d_in[1];
    const float* b1 = (const float*)d_in[2];
    const float* W2 = (const float*)d_in[3];
    const float* b2 = (const float*)d_in[4];
    const float* W3 = (const float*)d_in[5];
    const float* b3 = (const float*)d_in[6];
    const float* W4 = (const float*)d_in[7];
    const float* b4 = (const float*)d_in[8];
    const int* ei    = (const int*)d_in[9];
    const int* batch = (const int*)d_in[10];

    const int N = in_sizes[0] / HDIM;   // 50000 (NOTE: 16-bit src packing needs N<65536)
    const int E = in_sizes[9] / 2;      // 640000
    const int G = out_size / 2;         // 64
    const int* src = ei;
    const int* dst = ei + E;

    const int nbuck = (N + 255) >> 8;        // 196 (must be <= 256)
    const int nscan = nbuck * NBLK;          // 50176
    const int chunk = (E + NBLK - 1) / NBLK; // 2500

    // ---- workspace layout (16B-aligned blocks) ----
    const int Nr = ((N + 63) / 64) * 64;
    char* wsb = (char*)d_ws;
    size_t o = 0;
    unsigned int* g = (unsigned int*)(wsb + o); o += (size_t)G * HDIM * 4;
    size_t zero_bytes = o;                 // only g needs zeroing
    int* hist = (int*)(wsb + o);           o += (size_t)nscan * 4;
    int* hscan = (int*)(wsb + o);          o += (size_t)nscan * 4;
    int* sums = (int*)(wsb + o);           o += 256 * 4;
    int* rowstart = (int*)(wsb + o);       o += (size_t)(Nr + 64) * 4;
    float* dinv = (float*)(wsb + o);       o += (size_t)Nr * 4;
    int* sorted = (int*)(wsb + o);         o += (size_t)E * 4;    // packed 4B/edge
    int* csr = (int*)(wsb + o);            o += (size_t)E * 4;
    unsigned short* wf1h = (unsigned short*)(wsb + o); o += (size_t)HDIM * HDIM * 2;
    unsigned short* wf1l = (unsigned short*)(wsb + o); o += (size_t)HDIM * HDIM * 2;
    unsigned short* wf2h = (unsigned short*)(wsb + o); o += (size_t)HDIM * HDIM * 2;
    unsigned short* wf2l = (unsigned short*)(wsb + o); o += (size_t)HDIM * HDIM * 2;
    unsigned short* m = (unsigned short*)(wsb + o);    o += (size_t)Nr * HDIM * 2;
    unsigned short* m2 = (unsigned short*)(wsb + o);   o += (size_t)Nr * HDIM * 2;
    (void)ws_size; (void)n_in;

    (void)hipMemsetAsync(d_ws, 0, zero_bytes, stream);

    int sblocks = (nscan + SCAN_B - 1) / SCAN_B;   // 196 (<= 256 required)
    int gemm_blocks = (N + GBM - 1) / GBM;         // 782
    int agg_blocks = (N + 31) / 32;                // 1563

    // K1: hist || wfrag  (independent)
    mega1_kernel<<<NBLK + 128, 256, 0, stream>>>(dst, hist, E, chunk, nbuck,
                                                 W1, W2, wf1h, wf1l, wf2h, wf2l);
    // K2: scan of hist matrix -> hscan exclusive (scan2 folded into scan3)
    scan1_kernel<<<sblocks, SCAN_B, 0, stream>>>(hist, hscan, sums, nscan);
    scan3_kernel<<<sblocks, SCAN_B, 0, stream>>>(hist, hscan, sums, nscan, sblocks);
    // K3: scatter (bucket sort, packed 4B) || gemm layer 1
    mega3_kernel<<<NBLK + gemm_blocks, 256, 0, stream>>>(src, dst, hscan, sorted,
                                                         E, chunk, nbuck,
                                                         x, wf1h, wf1l, m, N);
    // K4: per-bucket CSR build (rowstart, dinv, csr)
    csr_kernel<<<nbuck, 256, 0, stream>>>(sorted, hscan, rowstart, dinv, csr, N, E, nbuck);
    // K5: fused agg(layer1) + gemm(layer2) -> m2
    agg_gemm_kernel<<<agg_blocks, 256, 0, stream>>>((const uint4*)m, rowstart, csr,
                                                    dinv, b1, wf2h, wf2l,
                                                    (uint4*)m2, N);
    // K6: agg layer 2 + global max pool
    agg_pool_kernel<<<agg_blocks, 256, 0, stream>>>((const uint4*)m2, rowstart, csr,
                                                    dinv, b2, batch, g, N);
    // K7: MLP head + log_softmax
    mlp_kernel<<<G, 128, 0, stream>>>(g, W3, b3, W4, b4, (float*)d_out);
}

// Round 11
// 202.800 us; speedup vs baseline: 1.0494x; 1.0494x over previous
//
#include <hip/hip_runtime.h>
#include <hip/hip_bf16.h>
#include <math.h>

// ---------------- constants ----------------
#define HDIM 128
#define SCAN_B 256
#define NBLK 256          // edge blocks for hist/scatter passes

typedef short bfrag __attribute__((ext_vector_type(8)));   // 8 bf16 (4 VGPRs)
typedef float f32x4 __attribute__((ext_vector_type(4)));   // 4 fp32 acc

__device__ inline unsigned short f2bf_rne(float x) {
    unsigned u = __float_as_uint(x);
    u = (u + 0x7fffu + ((u >> 16) & 1u)) >> 16;
    return (unsigned short)u;
}
__device__ inline float bf_lo(unsigned u) { return __uint_as_float(u << 16); }
__device__ inline float bf_hi(unsigned u) { return __uint_as_float(u & 0xffff0000u); }

// ---------------- device bodies ----------------

// Pass A: per-block LDS histogram over coarse buckets (dst>>8); no global atomics.
__device__ inline void hist_body(int b, const int* __restrict__ dst,
                                 int* __restrict__ hist, int E, int chunk, int nbuck) {
    __shared__ int hl[256];
    int t = threadIdx.x;
    hl[t] = 0;
    __syncthreads();
    int start = b * chunk, end = min(E, start + chunk);
    for (int e = start + t; e < end; e += 256) atomicAdd(&hl[dst[e] >> 8], 1);
    __syncthreads();
    if (t < nbuck) hist[t * NBLK + b] = hl[t];
}

// W -> fragment-ordered bf16 hi/lo, column-permuted: physical slot (nt, lm)
// carries logical column n_l = lm*8 + nt (so epilogue stores are 16B packed).
__device__ inline void wfrag_body(int b, const float* __restrict__ W1,
                                  const float* __restrict__ W2,
                                  unsigned short* __restrict__ w1h,
                                  unsigned short* __restrict__ w1l,
                                  unsigned short* __restrict__ w2h,
                                  unsigned short* __restrict__ w2l) {
    const float* W = (b < 64) ? W1 : W2;
    unsigned short* whi = (b < 64) ? w1h : w2h;
    unsigned short* wlo = (b < 64) ? w1l : w2l;
    int idx = (b & 63) * 256 + threadIdx.x;     // 0..16383
    int k = idx >> 7;
    int n = idx & 127;
    int kt = k >> 5, q = (k >> 3) & 3, j = k & 7;
    int lm = n >> 3, nt = n & 7;
    int lane = q * 16 + lm;
    int o = ((kt * 8 + nt) * 64 + lane) * 8 + j;
    float x = W[idx];
    unsigned short hb = f2bf_rne(x);
    float hf = __uint_as_float(((unsigned)hb) << 16);
    unsigned short lb = f2bf_rne(x - hf);
    whi[o] = hb;
    wlo[o] = lb;
}

// Pass C: scatter edges into bucket-sorted order via LDS cursors.
// Packed entry: src (16b, N=50000<65536) | (dst&255)<<16  -- 4B/edge.
__device__ inline void scatter_body(int b, const int* __restrict__ srcv,
                                    const int* __restrict__ dstv,
                                    const int* __restrict__ hscan,
                                    int* __restrict__ sorted,
                                    int E, int chunk, int nbuck) {
    __shared__ int cur[256];
    int t = threadIdx.x;
    if (t < nbuck) cur[t] = hscan[t * NBLK + b];
    __syncthreads();
    int start = b * chunk, end = min(E, start + chunk);
    for (int e = start + t; e < end; e += 256) {
        int d = dstv[e];
        int pos = atomicAdd(&cur[d >> 8], 1);
        sorted[pos] = srcv[e] | ((d & 255) << 16);
    }
}

// MFMA GEMM (fp32 A), 64-row tiles, split 3-MFMA: C ~= Ah*Wh + Al*Wh + Ah*Wl
#define GBM 64
__device__ inline void gemm_f32_body(int b, const float* __restrict__ A,
                                     const unsigned short* __restrict__ whi,
                                     const unsigned short* __restrict__ wlo,
                                     unsigned short* __restrict__ C, int Nrows) {
    int tid = threadIdx.x;
    int w = tid >> 6, L = tid & 63;
    int lm = L & 15, lq = L >> 4;
    int row0 = b * GBM + w * 16;

    f32x4 acc[8];
#pragma unroll
    for (int nt = 0; nt < 8; ++nt) acc[nt] = (f32x4)(0.f);

#pragma unroll
    for (int kt = 0; kt < 4; ++kt) {
        int gr = row0 + lm;
        float4 v0 = make_float4(0.f, 0.f, 0.f, 0.f);
        float4 v1 = v0;
        if (gr < Nrows) {
            const float* p = &A[(size_t)gr * HDIM + kt * 32 + lq * 8];
            v0 = *(const float4*)p;
            v1 = *(const float4*)(p + 4);
        }
        float xv[8] = {v0.x, v0.y, v0.z, v0.w, v1.x, v1.y, v1.z, v1.w};
        bfrag ah, al;
#pragma unroll
        for (int j = 0; j < 8; ++j) {
            float x = xv[j];
            unsigned short hb = f2bf_rne(x);
            float hf = __uint_as_float(((unsigned)hb) << 16);
            unsigned short lb = f2bf_rne(x - hf);
            ah[j] = (short)hb;
            al[j] = (short)lb;
        }
#pragma unroll
        for (int nt = 0; nt < 8; ++nt) {
            int o = ((kt * 8 + nt) * 64 + L) * 8;
            bfrag wh = *(const bfrag*)&whi[o];
            bfrag wl = *(const bfrag*)&wlo[o];
            acc[nt] = __builtin_amdgcn_mfma_f32_16x16x32_bf16(ah, wh, acc[nt], 0, 0, 0);
            acc[nt] = __builtin_amdgcn_mfma_f32_16x16x32_bf16(al, wh, acc[nt], 0, 0, 0);
            acc[nt] = __builtin_amdgcn_mfma_f32_16x16x32_bf16(ah, wl, acc[nt], 0, 0, 0);
        }
    }

#pragma unroll
    for (int i = 0; i < 4; ++i) {
        int gr = row0 + lq * 4 + i;
        if (gr < Nrows) {
            bfrag e;
#pragma unroll
            for (int nt = 0; nt < 8; ++nt) e[nt] = (short)f2bf_rne(acc[nt][i]);
            *(bfrag*)&C[(size_t)gr * HDIM + lm * 8] = e;
        }
    }
}

// ---------------- megakernel 1: hist || wfrag ----------------
__global__ __launch_bounds__(256) void mega1_kernel(const int* __restrict__ dst,
                                                    int* __restrict__ hist, int E,
                                                    int chunk, int nbuck,
                                                    const float* __restrict__ W1,
                                                    const float* __restrict__ W2,
                                                    unsigned short* __restrict__ w1h,
                                                    unsigned short* __restrict__ w1l,
                                                    unsigned short* __restrict__ w2h,
                                                    unsigned short* __restrict__ w2l) {
    int b = blockIdx.x;
    if (b < NBLK) hist_body(b, dst, hist, E, chunk, nbuck);
    else wfrag_body(b - NBLK, W1, W2, w1h, w1l, w2h, w2l);
}

// ---------------- megakernel 3: scatter || gemm_f32(layer1) ----------------
__global__ __launch_bounds__(256) void mega3_kernel(const int* __restrict__ srcv,
                                                    const int* __restrict__ dstv,
                                                    const int* __restrict__ hscan,
                                                    int* __restrict__ sorted,
                                                    int E, int chunk, int nbuck,
                                                    const float* __restrict__ A,
                                                    const unsigned short* __restrict__ whi,
                                                    const unsigned short* __restrict__ wlo,
                                                    unsigned short* __restrict__ C, int Nrows) {
    int b = blockIdx.x;
    if (b < NBLK) scatter_body(b, srcv, dstv, hscan, sorted, E, chunk, nbuck);
    else gemm_f32_body(b - NBLK, A, whi, wlo, C, Nrows);
}

// ---------------- scan: phase 1 (block-local inclusive + block sums) ----------------
__global__ __launch_bounds__(SCAN_B) void scan1_kernel(const int* __restrict__ in,
                                                       int* __restrict__ out,
                                                       int* __restrict__ sums, int n) {
    __shared__ int s[SCAN_B];
    int t = threadIdx.x;
    int idx = blockIdx.x * SCAN_B + t;
    int v = (idx < n) ? in[idx] : 0;
    s[t] = v;
    __syncthreads();
    for (int off = 1; off < SCAN_B; off <<= 1) {
        int x = (t >= off) ? s[t - off] : 0;
        __syncthreads();
        s[t] += x;
        __syncthreads();
    }
    if (idx < n) out[idx] = s[t];
    if (t == SCAN_B - 1) sums[blockIdx.x] = s[t];
}

// scan phase 2+3 fused: every block re-scans the (raw) block sums in LDS,
// takes its own exclusive base, finalizes out[] to global exclusive scan.
__global__ __launch_bounds__(SCAN_B) void scan3_kernel(const int* __restrict__ in,
                                                       int* __restrict__ out,
                                                       const int* __restrict__ sums,
                                                       int n, int nb) {
    __shared__ int s[SCAN_B];
    int t = threadIdx.x;
    int v = (t < nb) ? sums[t] : 0;
    s[t] = v;
    __syncthreads();
    for (int off = 1; off < SCAN_B; off <<= 1) {
        int x = (t >= off) ? s[t - off] : 0;
        __syncthreads();
        s[t] += x;
        __syncthreads();
    }
    int base = (blockIdx.x > 0) ? s[blockIdx.x - 1] : 0;
    int idx = blockIdx.x * SCAN_B + t;
    if (idx < n) out[idx] = out[idx] - in[idx] + base;
}

// ---------------- Pass D: per-bucket CSR build (LDS atomics only) ----------------
__global__ __launch_bounds__(256) void csr_kernel(const int* __restrict__ sorted,
                                                  const int* __restrict__ hscan,
                                                  int* __restrict__ rowstart,
                                                  float* __restrict__ dinv,
                                                  int* __restrict__ csr,
                                                  int N, int E, int nbuck) {
    __shared__ int cnt[256];
    __shared__ int s[256];
    __shared__ int cur[256];
    int b = blockIdx.x;
    int t = threadIdx.x;
    int start = hscan[b * NBLK];
    int end = (b + 1 < nbuck) ? hscan[(b + 1) * NBLK] : E;
    cnt[t] = 0;
    __syncthreads();
    for (int e = start + t; e < end; e += 256)
        atomicAdd(&cnt[(sorted[e] >> 16) & 255], 1);
    __syncthreads();
    int v = cnt[t];
    s[t] = v;
    __syncthreads();
    for (int off = 1; off < 256; off <<= 1) {
        int x = (t >= off) ? s[t - off] : 0;
        __syncthreads();
        s[t] += x;
        __syncthreads();
    }
    int excl = s[t] - v;
    int node = b * 256 + t;
    if (node < N) {
        rowstart[node] = start + excl;
        dinv[node] = rsqrtf((float)(v + 1));   // +1 self-loop
    }
    if (b == nbuck - 1 && t == 0) rowstart[N] = E;
    cur[t] = start + excl;
    __syncthreads();
    for (int e = start + t; e < end; e += 256) {
        int ed = sorted[e];
        int pos = atomicAdd(&cur[(ed >> 16) & 255], 1);
        csr[pos] = ed & 0xFFFF;
    }
}

// ---------------- quarter-wave gather, 8-deep software pipeline ----------------
#define QACC(UV, WT)                                   \
    acc[0] = fmaf(WT, bf_lo((UV).x), acc[0]);          \
    acc[1] = fmaf(WT, bf_hi((UV).x), acc[1]);          \
    acc[2] = fmaf(WT, bf_lo((UV).y), acc[2]);          \
    acc[3] = fmaf(WT, bf_hi((UV).y), acc[3]);          \
    acc[4] = fmaf(WT, bf_lo((UV).z), acc[4]);          \
    acc[5] = fmaf(WT, bf_hi((UV).z), acc[5]);          \
    acc[6] = fmaf(WT, bf_lo((UV).w), acc[6]);          \
    acc[7] = fmaf(WT, bf_hi((UV).w), acc[7]);

__device__ inline void qgather(const uint4* __restrict__ m4,
                               const int* __restrict__ csr,
                               const float* __restrict__ dinv,
                               int p, int pend, int t, float* acc) {
    for (; p + 8 <= pend; p += 8) {
        int s0 = csr[p], s1 = csr[p + 1], s2 = csr[p + 2], s3 = csr[p + 3];
        int s4 = csr[p + 4], s5 = csr[p + 5], s6 = csr[p + 6], s7 = csr[p + 7];
        float w0 = dinv[s0], w1 = dinv[s1], w2 = dinv[s2], w3 = dinv[s3];
        float w4 = dinv[s4], w5 = dinv[s5], w6 = dinv[s6], w7 = dinv[s7];
        uint4 u0 = m4[(size_t)s0 * 16 + t];
        uint4 u1 = m4[(size_t)s1 * 16 + t];
        uint4 u2 = m4[(size_t)s2 * 16 + t];
        uint4 u3 = m4[(size_t)s3 * 16 + t];
        uint4 u4 = m4[(size_t)s4 * 16 + t];
        uint4 u5 = m4[(size_t)s5 * 16 + t];
        uint4 u6 = m4[(size_t)s6 * 16 + t];
        uint4 u7 = m4[(size_t)s7 * 16 + t];
        QACC(u0, w0); QACC(u1, w1); QACC(u2, w2); QACC(u3, w3);
        QACC(u4, w4); QACC(u5, w5); QACC(u6, w6); QACC(u7, w7);
    }
    if (p + 4 <= pend) {
        int s0 = csr[p], s1 = csr[p + 1], s2 = csr[p + 2], s3 = csr[p + 3];
        float w0 = dinv[s0], w1 = dinv[s1], w2 = dinv[s2], w3 = dinv[s3];
        uint4 u0 = m4[(size_t)s0 * 16 + t];
        uint4 u1 = m4[(size_t)s1 * 16 + t];
        uint4 u2 = m4[(size_t)s2 * 16 + t];
        uint4 u3 = m4[(size_t)s3 * 16 + t];
        QACC(u0, w0); QACC(u1, w1); QACC(u2, w2); QACC(u3, w3);
        p += 4;
    }
    if (p + 2 <= pend) {
        int s0 = csr[p], s1 = csr[p + 1];
        float w0 = dinv[s0], w1 = dinv[s1];
        uint4 u0 = m4[(size_t)s0 * 16 + t];
        uint4 u1 = m4[(size_t)s1 * 16 + t];
        QACC(u0, w0); QACC(u1, w1);
        p += 2;
    }
    if (p < pend) {
        int s0 = csr[p];
        float w0 = dinv[s0];
        uint4 u0 = m4[(size_t)s0 * 16 + t];
        QACC(u0, w0);
    }
}

// ---------------- fused agg(layer1) + gemm(layer2): 16 nodes/block ----------------
// LDS: cbuf (fp32 C tile) overlaid on hbuf via union-style layout; hbuf is dead
// after the MFMA loop (extra barrier), so total LDS = max(8.5K) not sum.
__global__ __launch_bounds__(256) void agg_gemm_kernel(
        const uint4* __restrict__ m4,
        const int* __restrict__ rowstart,
        const int* __restrict__ csr,
        const float* __restrict__ dinv,
        const float* __restrict__ bias,
        const unsigned short* __restrict__ whi,   // W2 frags
        const unsigned short* __restrict__ wlo,
        uint4* __restrict__ out_m, int n) {
    __shared__ float lds[16 * (HDIM + 4)];          // 8448 B, dual-purpose
    unsigned short* hbuf = (unsigned short*)lds;    // [16][HDIM+8] view (4352 B)
    int t = threadIdx.x & 15;
    int nl = threadIdx.x >> 4;
    int node = blockIdx.x * 16 + nl;

    // ---- agg phase ----
    unsigned short hv[8] = {0, 0, 0, 0, 0, 0, 0, 0};
    if (node < n) {
        float dd = dinv[node];
        float acc[8];
        uint4 u = m4[(size_t)node * 16 + t];
        acc[0] = dd * bf_lo(u.x); acc[1] = dd * bf_hi(u.x);
        acc[2] = dd * bf_lo(u.y); acc[3] = dd * bf_hi(u.y);
        acc[4] = dd * bf_lo(u.z); acc[5] = dd * bf_hi(u.z);
        acc[6] = dd * bf_lo(u.w); acc[7] = dd * bf_hi(u.w);
        qgather(m4, csr, dinv, rowstart[node], rowstart[node + 1], t, acc);
        float4 b0 = *(const float4*)&bias[t * 8];
        float4 b1 = *(const float4*)&bias[t * 8 + 4];
        float bb[8] = {b0.x, b0.y, b0.z, b0.w, b1.x, b1.y, b1.z, b1.w};
#pragma unroll
        for (int j = 0; j < 8; ++j)
            hv[j] = f2bf_rne(fmaxf(fmaf(dd, acc[j], bb[j]), 0.f));
    }
    *(uint4*)&hbuf[nl * (HDIM + 8) + t * 8] = *(uint4*)hv;
    __syncthreads();

    // ---- gemm phase: each wave does 2 column tiles, all 4 kt ----
    int w = threadIdx.x >> 6, L = threadIdx.x & 63;
    int lm = L & 15, lq = L >> 4;
    f32x4 acc2[2];
    acc2[0] = (f32x4)(0.f);
    acc2[1] = (f32x4)(0.f);
#pragma unroll
    for (int kt = 0; kt < 4; ++kt) {
        bfrag a = *(const bfrag*)&hbuf[lm * (HDIM + 8) + kt * 32 + lq * 8];
#pragma unroll
        for (int q2 = 0; q2 < 2; ++q2) {
            int nt = w * 2 + q2;
            int o = ((kt * 8 + nt) * 64 + L) * 8;
            bfrag wh = *(const bfrag*)&whi[o];
            bfrag wl = *(const bfrag*)&wlo[o];
            acc2[q2] = __builtin_amdgcn_mfma_f32_16x16x32_bf16(a, wh, acc2[q2], 0, 0, 0);
            acc2[q2] = __builtin_amdgcn_mfma_f32_16x16x32_bf16(a, wl, acc2[q2], 0, 0, 0);
        }
    }
    __syncthreads();   // hbuf dead; reuse LDS as cbuf

    float* cbuf = lds; // [16][HDIM+4] view
    // C/D layout: col(in tile)=lane&15, row=(lane>>4)*4+i; logical col = lm*8+nt
#pragma unroll
    for (int q2 = 0; q2 < 2; ++q2) {
        int nt = w * 2 + q2;
#pragma unroll
        for (int i = 0; i < 4; ++i)
            cbuf[(lq * 4 + i) * (HDIM + 4) + lm * 8 + nt] = acc2[q2][i];
    }
    __syncthreads();

    // ---- repack + round + store ----
    if (node < n) {
        float4 r0 = *(const float4*)&cbuf[nl * (HDIM + 4) + t * 8];
        float4 r1 = *(const float4*)&cbuf[nl * (HDIM + 4) + t * 8 + 4];
        unsigned short ev[8];
        ev[0] = f2bf_rne(r0.x); ev[1] = f2bf_rne(r0.y);
        ev[2] = f2bf_rne(r0.z); ev[3] = f2bf_rne(r0.w);
        ev[4] = f2bf_rne(r1.x); ev[5] = f2bf_rne(r1.y);
        ev[6] = f2bf_rne(r1.z); ev[7] = f2bf_rne(r1.w);
        out_m[(size_t)node * 16 + t] = *(uint4*)ev;
    }
}

// ---------------- agg layer 2 fused with global max pool: 16 nodes/block ----------------
__global__ __launch_bounds__(256) void agg_pool_kernel(const uint4* __restrict__ m4,
                                                       const int* __restrict__ rowstart,
                                                       const int* __restrict__ csr,
                                                       const float* __restrict__ dinv,
                                                       const float* __restrict__ bias,
                                                       const int* __restrict__ batch,
                                                       unsigned int* __restrict__ g, int n) {
    __shared__ float smx[16][HDIM];
    __shared__ int sgid[16];
    int t = threadIdx.x & 15;
    int nl = threadIdx.x >> 4;              // node-in-block 0..15
    int node = blockIdx.x * 16 + nl;
    bool valid = node < n;
    if (valid) {
        float dd = dinv[node];
        float acc[8];
        uint4 u = m4[(size_t)node * 16 + t];
        acc[0] = dd * bf_lo(u.x); acc[1] = dd * bf_hi(u.x);
        acc[2] = dd * bf_lo(u.y); acc[3] = dd * bf_hi(u.y);
        acc[4] = dd * bf_lo(u.z); acc[5] = dd * bf_hi(u.z);
        acc[6] = dd * bf_lo(u.w); acc[7] = dd * bf_hi(u.w);
        qgather(m4, csr, dinv, rowstart[node], rowstart[node + 1], t, acc);
        float4 b0 = *(const float4*)&bias[t * 8];
        float4 b1 = *(const float4*)&bias[t * 8 + 4];
        float4 r0, r1;
        r0.x = fmaxf(fmaf(dd, acc[0], b0.x), 0.f);
        r0.y = fmaxf(fmaf(dd, acc[1], b0.y), 0.f);
        r0.z = fmaxf(fmaf(dd, acc[2], b0.z), 0.f);
        r0.w = fmaxf(fmaf(dd, acc[3], b0.w), 0.f);
        r1.x = fmaxf(fmaf(dd, acc[4], b1.x), 0.f);
        r1.y = fmaxf(fmaf(dd, acc[5], b1.y), 0.f);
        r1.z = fmaxf(fmaf(dd, acc[6], b1.z), 0.f);
        r1.w = fmaxf(fmaf(dd, acc[7], b1.w), 0.f);
        *(float4*)&smx[nl][t * 8] = r0;
        *(float4*)&smx[nl][t * 8 + 4] = r1;
    }
    if (t == 0) sgid[nl] = valid ? batch[node] : -1;
    __syncthreads();
    if (threadIdx.x < HDIM) {
        int c = threadIdx.x;
        int curg = -1;
        float run = 0.f;
#pragma unroll
        for (int r = 0; r < 16; ++r) {
            int gg = sgid[r];
            if (gg < 0) continue;
            if (gg != curg) {
                if (curg >= 0) atomicMax(&g[curg * HDIM + c], __float_as_uint(run));
                curg = gg;
                run = smx[r][c];
            } else {
                run = fmaxf(run, smx[r][c]);
            }
        }
        if (curg >= 0) atomicMax(&g[curg * HDIM + c], __float_as_uint(run));
    }
}

// ---------------- MLP head + log_softmax ----------------
__global__ __launch_bounds__(128) void mlp_kernel(const unsigned int* __restrict__ gbits,
                                                  const float* __restrict__ W3,
                                                  const float* __restrict__ b3,
                                                  const float* __restrict__ W4,
                                                  const float* __restrict__ b4,
                                                  float* __restrict__ out) {
    __shared__ float gs[HDIM];
    __shared__ float r0[HDIM];
    __shared__ float r1[HDIM];
    int j = threadIdx.x;
    int b = blockIdx.x;
    gs[j] = __uint_as_float(gbits[b * HDIM + j]);
    __syncthreads();
    float acc = b3[j];
#pragma unroll 8
    for (int k = 0; k < HDIM; ++k) acc = fmaf(gs[k], W3[k * HDIM + j], acc);
    float z = fmaxf(acc, 0.f);
    r0[j] = z * W4[j * 2 + 0];
    r1[j] = z * W4[j * 2 + 1];
    __syncthreads();
    for (int off = 64; off > 0; off >>= 1) {
        if (j < off) {
            r0[j] += r0[j + off];
            r1[j] += r1[j + off];
        }
        __syncthreads();
    }
    if (j == 0) {
        float l0 = r0[0] + b4[0];
        float l1 = r1[0] + b4[1];
        float mx = fmaxf(l0, l1);
        float lse = mx + logf(expf(l0 - mx) + expf(l1 - mx));
        out[b * 2 + 0] = l0 - lse;
        out[b * 2 + 1] = l1 - lse;
    }
}

extern "C" void kernel_launch(void* const* d_in, const int* in_sizes, int n_in,
                              void* d_out, int out_size, void* d_ws, size_t ws_size,
                              hipStream_t stream) {
    const float* x  = (const float*)d_in[0];
    const float* W1 = (const float*)d_in[1];
    const float* b1 = (const float*)d_in[2];
    const float* W2 = (const float*)d_in[3];
    const float* b2 = (const float*)d_in[4];
    const float* W3 = (const float*)d_in[5];
    const float* b3 = (const float*)d_in[6];
    const float* W4 = (const float*)d_in[7];
    const float* b4 = (const float*)d_in[8];
    const int* ei    = (const int*)d_in[9];
    const int* batch = (const int*)d_in[10];

    const int N = in_sizes[0] / HDIM;   // 50000 (NOTE: 16-bit src packing needs N<65536)
    const int E = in_sizes[9] / 2;      // 640000
    const int G = out_size / 2;         // 64
    const int* src = ei;
    const int* dst = ei + E;

    const int nbuck = (N + 255) >> 8;        // 196 (must be <= 256)
    const int nscan = nbuck * NBLK;          // 50176
    const int chunk = (E + NBLK - 1) / NBLK; // 2500

    // ---- workspace layout (16B-aligned blocks) ----
    const int Nr = ((N + 63) / 64) * 64;
    char* wsb = (char*)d_ws;
    size_t o = 0;
    unsigned int* g = (unsigned int*)(wsb + o); o += (size_t)G * HDIM * 4;
    size_t zero_bytes = o;                 // only g needs zeroing
    int* hist = (int*)(wsb + o);           o += (size_t)nscan * 4;
    int* hscan = (int*)(wsb + o);          o += (size_t)nscan * 4;
    int* sums = (int*)(wsb + o);           o += 256 * 4;
    int* rowstart = (int*)(wsb + o);       o += (size_t)(Nr + 64) * 4;
    float* dinv = (float*)(wsb + o);       o += (size_t)Nr * 4;
    int* sorted = (int*)(wsb + o);         o += (size_t)E * 4;    // packed 4B/edge
    int* csr = (int*)(wsb + o);            o += (size_t)E * 4;
    unsigned short* wf1h = (unsigned short*)(wsb + o); o += (size_t)HDIM * HDIM * 2;
    unsigned short* wf1l = (unsigned short*)(wsb + o); o += (size_t)HDIM * HDIM * 2;
    unsigned short* wf2h = (unsigned short*)(wsb + o); o += (size_t)HDIM * HDIM * 2;
    unsigned short* wf2l = (unsigned short*)(wsb + o); o += (size_t)HDIM * HDIM * 2;
    unsigned short* m = (unsigned short*)(wsb + o);    o += (size_t)Nr * HDIM * 2;
    unsigned short* m2 = (unsigned short*)(wsb + o);   o += (size_t)Nr * HDIM * 2;
    (void)ws_size; (void)n_in;

    (void)hipMemsetAsync(d_ws, 0, zero_bytes, stream);

    int sblocks = (nscan + SCAN_B - 1) / SCAN_B;   // 196 (<= 256 required)
    int gemm_blocks = (N + GBM - 1) / GBM;         // 782
    int agg_blocks = (N + 15) / 16;                // 3125

    // K1: hist || wfrag  (independent)
    mega1_kernel<<<NBLK + 128, 256, 0, stream>>>(dst, hist, E, chunk, nbuck,
                                                 W1, W2, wf1h, wf1l, wf2h, wf2l);
    // K2: scan of hist matrix -> hscan exclusive (scan2 folded into scan3)
    scan1_kernel<<<sblocks, SCAN_B, 0, stream>>>(hist, hscan, sums, nscan);
    scan3_kernel<<<sblocks, SCAN_B, 0, stream>>>(hist, hscan, sums, nscan, sblocks);
    // K3: scatter (bucket sort, packed 4B) || gemm layer 1
    mega3_kernel<<<NBLK + gemm_blocks, 256, 0, stream>>>(src, dst, hscan, sorted,
                                                         E, chunk, nbuck,
                                                         x, wf1h, wf1l, m, N);
    // K4: per-bucket CSR build (rowstart, dinv, csr)
    csr_kernel<<<nbuck, 256, 0, stream>>>(sorted, hscan, rowstart, dinv, csr, N, E, nbuck);
    // K5: fused agg(layer1) + gemm(layer2) -> m2
    agg_gemm_kernel<<<agg_blocks, 256, 0, stream>>>((const uint4*)m, rowstart, csr,
                                                    dinv, b1, wf2h, wf2l,
                                                    (uint4*)m2, N);
    // K6: agg layer 2 + global max pool
    agg_pool_kernel<<<agg_blocks, 256, 0, stream>>>((const uint4*)m2, rowstart, csr,
                                                    dinv, b2, batch, g, N);
    // K7: MLP head + log_softmax
    mlp_kernel<<<G, 128, 0, stream>>>(g, W3, b3, W4, b4, (float*)d_out);
}